// Round 13
// baseline (386.296 us; speedup 1.0000x reference)
//
#include <hip/hip_runtime.h>
#include <hip/hip_bf16.h>

// ---------------------------------------------------------------------------
// CustomTransformerLayer: QK proj -> scores -> softmax -> PV -> Wo -> LN1
//                         -> FF1(relu) -> FF2 -> LN2.  V^T computed directly
//                         as a GEMM (no explicit transpose).
// B=4, S=2048, E=1024, FF=4096.  GEMMs: fp16 MFMA 16x16x32, fp32 acc.
// R13: un-pinned MFMA clusters (no lgkmcnt(0)/sched_barrier(0) pin) — the
// compiler emits counted lgkm waits per consuming MFMA (m97/m141 evidence);
// reads are SSA-visible so correctness is barrier+in-order-issue guaranteed.
// ---------------------------------------------------------------------------

using u16 = unsigned short;
typedef __attribute__((ext_vector_type(8))) _Float16 half8;
typedef __attribute__((ext_vector_type(4))) float f32x4;

#define BATCH 4
#define SEQ   2048
#define EMB   1024
#define FFD   4096

#define SWZ(r) ((((r) >> 1) & 3) << 4)

__device__ __forceinline__ u16 f2h(float f) {
    union { _Float16 h; u16 u; } x;
    x.h = (_Float16)f;
    return x.u;
}
__device__ __forceinline__ float h2f(u16 u) {
    union { u16 u; _Float16 h; } x;
    x.u = u;
    return (float)x.h;
}

typedef const __attribute__((address_space(1))) void* gas_ptr;
typedef __attribute__((address_space(3))) void* las_ptr;

__device__ __forceinline__ void load_lds16(const void* g, void* l) {
    __builtin_amdgcn_global_load_lds((gas_ptr)g, (las_ptr)l, 16, 0, 0);
}

// ---------------------------------------------------------------------------
// gemm_8p: 256x256x64 tile, 8 waves (2Mx4N), wave 128x64.  [R8 structure,
// MFMA cluster un-pinned]
// ---------------------------------------------------------------------------
template <typename OutT, bool RELU, bool BIAS>
__global__ __launch_bounds__(512, 2) void gemm_8p(
    const u16* __restrict__ A, const u16* __restrict__ Bt,
    OutT* __restrict__ C, const float* __restrict__ bias,
    int N, int K, int lda, int ldb, int ldc, long sA, long sB, long sC)
{
    constexpr int BUF = 65536;
    __shared__ __attribute__((aligned(16))) char lds[2 * BUF];

    A  += (long)blockIdx.z * sA;
    Bt += (long)blockIdx.z * sB;
    C  += (long)blockIdx.z * sC;

    const int tid  = threadIdx.x;
    const int lane = tid & 63;
    const int wv   = tid >> 6;
    const int wm   = wv >> 2;
    const int wn   = wv & 3;
    const long row0 = (long)blockIdx.x * 256;
    const long col0 = (long)blockIdx.y * 256;

    long aS[2], bS[2]; int dD[2];
#pragma unroll
    for (int i = 0; i < 2; ++i) {
        const int d16 = i * 512 + tid;
        const int lrow = d16 >> 3;
        const int sl   = d16 & 7;
        const long cswz = (long)((sl ^ (lrow & 7)) << 3);
        aS[i] = (row0 + lrow) * (long)lda + cswz;
        bS[i] = (col0 + lrow) * (long)ldb + cswz;
        dD[i] = d16 * 16;
    }
    const long aHop = 128 * (long)lda;
    const long bHop = 128 * (long)ldb;

    const int klb = (lane >> 4) << 4;
    const int swz = (lane & 7) << 4;
    const int aRB = (wm * 128 + (lane & 15)) * 128 + (klb ^ swz);
    const int bRB = 32768 + (wn * 64 + (lane & 15)) * 128 + (klb ^ swz);

    f32x4 acc[8][4] = {};
    half8 a[8], b[4];
    const int G = K >> 6;

#define SGA(BUFB, H, KT)                                                      \
    { _Pragma("unroll") for (int i_ = 0; i_ < 2; ++i_)                        \
          load_lds16(A + aS[i_] + (H) * aHop + (long)(KT) * 64,               \
                     lds + (BUFB) + (H) * 16384 + dD[i_]); }
#define SGB(BUFB, H, KT)                                                      \
    { _Pragma("unroll") for (int i_ = 0; i_ < 2; ++i_)                        \
          load_lds16(Bt + bS[i_] + (H) * bHop + (long)(KT) * 64,              \
                     lds + (BUFB) + 32768 + (H) * 16384 + dD[i_]); }
#define NOP8 ((void)0)
#define VM8 asm volatile("s_waitcnt vmcnt(8)" ::: "memory")
#define VM6 asm volatile("s_waitcnt vmcnt(6)" ::: "memory")
#define VM2 asm volatile("s_waitcnt vmcnt(2)" ::: "memory")
#define VMZ asm volatile("s_waitcnt vmcnt(0)" ::: "memory")

#define PH8(BUFB, QM, QN, RDA, RDB, STG, VM)                                  \
    {                                                                         \
        if (RDA) {                                                            \
            _Pragma("unroll") for (int m_ = 0; m_ < 4; ++m_)                  \
            _Pragma("unroll") for (int k_ = 0; k_ < 2; ++k_)                  \
                a[m_ * 2 + k_] = *(const half8*)(lds + (BUFB) +               \
                    ((aRB + (QM) * 8192 + m_ * 2048) ^ (k_ << 6)));           \
        }                                                                     \
        if (RDB) {                                                            \
            _Pragma("unroll") for (int n_ = 0; n_ < 2; ++n_)                  \
            _Pragma("unroll") for (int k_ = 0; k_ < 2; ++k_)                  \
                b[n_ * 2 + k_] = *(const half8*)(lds + (BUFB) +               \
                    ((bRB + (QN) * 4096 + n_ * 2048) ^ (k_ << 6)));           \
        }                                                                     \
        STG; VM;                                                              \
        __builtin_amdgcn_s_barrier();                                         \
        __builtin_amdgcn_s_setprio(1);                                        \
        _Pragma("unroll") for (int k_ = 0; k_ < 2; ++k_)                      \
        _Pragma("unroll") for (int m_ = 0; m_ < 4; ++m_)                      \
        _Pragma("unroll") for (int n_ = 0; n_ < 2; ++n_)                      \
            acc[(QM) * 4 + m_][(QN) * 2 + n_] =                               \
                __builtin_amdgcn_mfma_f32_16x16x32_f16(                       \
                    a[m_ * 2 + k_], b[n_ * 2 + k_],                           \
                    acc[(QM) * 4 + m_][(QN) * 2 + n_], 0, 0, 0);              \
        __builtin_amdgcn_s_setprio(0);                                        \
        __builtin_amdgcn_s_barrier();                                         \
    }

    SGA(0, 0, 0); SGB(0, 1, 0); SGB(0, 0, 0); SGA(0, 1, 0);
    SGA(BUF, 0, 1); SGB(BUF, 1, 1);
    VM6;
    __builtin_amdgcn_s_barrier();

    for (int t = 0; t < G - 2; ++t) {
        const int cb = (t & 1) * BUF, ob = cb ^ BUF;
        PH8(cb, 0, 0, 1, 1, SGB(ob, 0, t + 1), NOP8)
        PH8(cb, 0, 1, 0, 1, SGA(ob, 1, t + 1), VM8)
        PH8(cb, 1, 1, 1, 0, SGA(cb, 0, t + 2), NOP8)
        PH8(cb, 1, 0, 0, 1, SGB(cb, 1, t + 2), VM6)
    }
    {
        const int cb = ((G - 2) & 1) * BUF, ob = cb ^ BUF;
        PH8(cb, 0, 0, 1, 1, SGB(ob, 0, G - 1), NOP8)
        PH8(cb, 0, 1, 0, 1, SGA(ob, 1, G - 1), VM8)
        PH8(cb, 1, 1, 1, 0, NOP8, NOP8)
        PH8(cb, 1, 0, 0, 1, NOP8, VM2)
    }
    {
        const int cb = ((G - 1) & 1) * BUF;
        PH8(cb, 0, 0, 1, 1, NOP8, NOP8)
        PH8(cb, 0, 1, 0, 1, NOP8, VMZ)
        PH8(cb, 1, 1, 1, 0, NOP8, NOP8)
        PH8(cb, 1, 0, 0, 1, NOP8, NOP8)
    }
#undef PH8
#undef SGA
#undef SGB
#undef NOP8
#undef VM8
#undef VM6
#undef VM2
#undef VMZ

    long cofs[4]; float bb[4];
#pragma unroll
    for (int n = 0; n < 4; ++n) {
        cofs[n] = col0 + wn * 64 + (n >> 1) * 32 + (n & 1) * 16 + (lane & 15);
        bb[n] = BIAS ? bias[cofs[n]] : 0.0f;
    }
#pragma unroll
    for (int m = 0; m < 8; ++m) {
#pragma unroll
        for (int r = 0; r < 4; ++r) {
            const long row = row0 + wm * 128 + (m >> 2) * 64 + (m & 3) * 16 +
                             ((lane >> 4) << 2) + r;
            OutT* Crow = C + row * (long)ldc;
#pragma unroll
            for (int n = 0; n < 4; ++n) {
                float v = acc[m][n][r] + bb[n];
                if (RELU) v = fmaxf(v, 0.0f);
                if constexpr (sizeof(OutT) == 2)
                    Crow[cofs[n]] = f2h(v);
                else
                    Crow[cofs[n]] = v;
            }
        }
    }
}

// ---------------------------------------------------------------------------
// gemm_dp:  BM x 256 tile, single-phase 32-K slab ring.  [R2 structure,
// trailing sched_barrier removed]
// BMODE: 0 = no bias, 1 = bias[col], 2 = bias[row]
// ---------------------------------------------------------------------------
template <int BM, typename OutT, bool RELU, int BMODE>
__global__ __launch_bounds__(512, 2) void gemm_dp(
    const u16* __restrict__ A, const u16* __restrict__ Bt,
    OutT* __restrict__ C, const float* __restrict__ bias,
    int N, int K, int lda, int ldb, int ldc, long sA, long sB, long sC)
{
    constexpr int MF = BM / 32;
    constexpr int AL = BM / 128;
    constexpr int SLAB_A = BM * 32;
    constexpr int SLAB_B = 256 * 32;

    __shared__ u16 ldsA[4 * SLAB_A];
    __shared__ u16 ldsB[4 * SLAB_B];

    A  += (long)blockIdx.z * sA;
    Bt += (long)blockIdx.z * sB;
    C  += (long)blockIdx.z * sC;

    const int tid  = threadIdx.x;
    const int lane = tid & 63;
    const int wv   = tid >> 6;
    const int wm   = wv >> 2;
    const int wn   = wv & 3;
    const long row0 = (long)blockIdx.x * BM;
    const long col0 = (long)blockIdx.y * 256;

    long aoff[AL]; int adst[AL];
#pragma unroll
    for (int i = 0; i < AL; ++i) {
        const int d16 = i * 512 + tid;
        const int row = d16 >> 2;
        const int colb = ((d16 & 3) << 4) ^ SWZ(row);
        aoff[i] = (row0 + row) * (long)lda + (colb >> 1);
        adst[i] = d16 * 16;
    }
    long boff[2]; int bdst[2];
#pragma unroll
    for (int i = 0; i < 2; ++i) {
        const int d16 = i * 512 + tid;
        const int row = d16 >> 2;
        const int colb = ((d16 & 3) << 4) ^ SWZ(row);
        boff[i] = (col0 + row) * (long)ldb + (colb >> 1);
        bdst[i] = d16 * 16;
    }

    int aro[MF], bro[4];
    const int klane = (lane >> 4) << 4;
#pragma unroll
    for (int m = 0; m < MF; ++m) {
        const int row = wm * (BM / 2) + m * 16 + (lane & 15);
        aro[m] = row * 64 + (klane ^ SWZ(row));
    }
#pragma unroll
    for (int n = 0; n < 4; ++n) {
        const int row = wn * 64 + n * 16 + (lane & 15);
        bro[n] = row * 64 + (klane ^ SWZ(row));
    }

    f32x4 acc[MF][4] = {};
    const int G = K >> 5;

    auto stage = [&](int g) {
        const int slot = g & 3;
        const long k0 = (long)g << 5;
#pragma unroll
        for (int i = 0; i < AL; ++i)
            load_lds16(A + aoff[i] + k0, (char*)ldsA + slot * (SLAB_A * 2) + adst[i]);
#pragma unroll
        for (int i = 0; i < 2; ++i)
            load_lds16(Bt + boff[i] + k0, (char*)ldsB + slot * (SLAB_B * 2) + bdst[i]);
    };

#define VMS asm volatile("s_waitcnt vmcnt(6)" ::: "memory")
#define VMT asm volatile("s_waitcnt vmcnt(3)" ::: "memory")
#define VM0 asm volatile("s_waitcnt vmcnt(0)" ::: "memory")
#define VMNONE ((void)0)

#define GBODY(g, VMASM, DOSTAGE)                                              \
    {                                                                         \
        const int slot_ = (g) & 3;                                            \
        const char* abase_ = (const char*)ldsA + slot_ * (SLAB_A * 2);        \
        const char* bbase_ = (const char*)ldsB + slot_ * (SLAB_B * 2);        \
        half8 a_[MF], b_[4];                                                  \
        _Pragma("unroll") for (int m = 0; m < MF; ++m)                        \
            a_[m] = *(const half8*)(abase_ + aro[m]);                         \
        _Pragma("unroll") for (int n = 0; n < 4; ++n)                         \
            b_[n] = *(const half8*)(bbase_ + bro[n]);                         \
        if (DOSTAGE) stage((g) + 3);                                          \
        VMASM;                                                                \
        __builtin_amdgcn_s_setprio(1);                                        \
        _Pragma("unroll") for (int m = 0; m < MF; ++m)                        \
            _Pragma("unroll") for (int n = 0; n < 4; ++n)                     \
                acc[m][n] = __builtin_amdgcn_mfma_f32_16x16x32_f16(           \
                    a_[m], b_[n], acc[m][n], 0, 0, 0);                        \
        __builtin_amdgcn_s_setprio(0);                                        \
        __builtin_amdgcn_s_barrier();                                         \
    }

    stage(0); stage(1); stage(2);
    VMS;
    __builtin_amdgcn_s_barrier();

    for (int g = 0; g < G - 3; ++g) GBODY(g, VMS, true)
    GBODY(G - 3, VMT, false)
    GBODY(G - 2, VM0, false)
    GBODY(G - 1, VMNONE, false)
#undef GBODY
#undef VMS
#undef VMT
#undef VM0
#undef VMNONE

#pragma unroll
    for (int n = 0; n < 4; ++n) {
        const long col = col0 + wn * 64 + n * 16 + (lane & 15);
        const float bc_ = (BMODE == 1) ? bias[col] : 0.0f;
#pragma unroll
        for (int m = 0; m < MF; ++m) {
            const long row = row0 + wm * (BM / 2) + m * 16 + ((lane >> 4) << 2);
#pragma unroll
            for (int r = 0; r < 4; ++r) {
                float v = acc[m][n][r] + bc_;
                if (BMODE == 2) v += bias[row + r];
                if (RELU) v = fmaxf(v, 0.0f);
                if constexpr (sizeof(OutT) == 2)
                    C[(row + r) * (long)ldc + col] = f2h(v);
                else
                    C[(row + r) * (long)ldc + col] = v;
            }
        }
    }
}

// ---------------------------------------------------------------------------
// batched fp32 [1024,1024] -> fp16 transposed:
//   z=0,1 -> WqkT halves; z=2 -> WvT; z=3 -> WoT
// ---------------------------------------------------------------------------
__global__ __launch_bounds__(256) void tc4(
    const float* __restrict__ s0, const float* __restrict__ s1,
    const float* __restrict__ s2, const float* __restrict__ s3,
    u16* __restrict__ dqk, u16* __restrict__ dwv, u16* __restrict__ dwo)
{
    __shared__ float t[32][33];
    const int z = blockIdx.z;
    const float* in = (z == 0) ? s0 : (z == 1) ? s1 : (z == 2) ? s2 : s3;
    u16* out = (z < 2) ? (dqk + (long)z * EMB * EMB) : (z == 2 ? dwv : dwo);
    const int bc = blockIdx.x * 32, br = blockIdx.y * 32;
    const int lx = threadIdx.x & 31, ly = threadIdx.x >> 5;
#pragma unroll
    for (int i = 0; i < 32; i += 8)
        t[ly + i][lx] = in[(long)(br + ly + i) * EMB + bc + lx];
    __syncthreads();
#pragma unroll
    for (int i = 0; i < 32; i += 8)
        out[(long)(bc + ly + i) * EMB + br + lx] = f2h(t[lx][ly + i]);
}

// fp32 [R,C] -> fp16 [C,R] transpose (rect weights)
__global__ __launch_bounds__(256) void transpose_cast(
    const float* __restrict__ in, u16* __restrict__ out, int R, int C)
{
    __shared__ float t[32][33];
    const int bc = blockIdx.x * 32, br = blockIdx.y * 32;
    const int lx = threadIdx.x & 31, ly = threadIdx.x >> 5;
#pragma unroll
    for (int i = 0; i < 32; i += 8)
        t[ly + i][lx] = in[(long)(br + ly + i) * C + bc + lx];
    __syncthreads();
#pragma unroll
    for (int i = 0; i < 32; i += 8)
        out[(long)(bc + ly + i) * R + br + lx] = f2h(t[lx][ly + i]);
}

// fp32 -> fp16 elementwise cast, 8 elems/thread
__global__ __launch_bounds__(256) void cast_h(
    const float* __restrict__ in, u16* __restrict__ out)
{
    const long i = ((long)blockIdx.x * 256 + threadIdx.x) * 8;
    const float4 a = ((const float4*)(in + i))[0];
    const float4 b = ((const float4*)(in + i))[1];
    union { u16 u[8]; uint4 v; } pk;
    pk.u[0] = f2h(a.x); pk.u[1] = f2h(a.y); pk.u[2] = f2h(a.z); pk.u[3] = f2h(a.w);
    pk.u[4] = f2h(b.x); pk.u[5] = f2h(b.y); pk.u[6] = f2h(b.z); pk.u[7] = f2h(b.w);
    *(uint4*)(out + i) = pk.v;
}

// bias concat: [bq|bk] -> 2048 fp32
__global__ __launch_bounds__(256) void concat_bias(
    const float* __restrict__ bq, const float* __restrict__ bk,
    float* __restrict__ o)
{
    const int i = blockIdx.x * 256 + threadIdx.x;
    o[i] = i < 1024 ? bq[i] : bk[i - 1024];
}

// ---------------------------------------------------------------------------
// row softmax: fp16 [rows,2048] -> fp16 [rows,2048], one block per row
// ---------------------------------------------------------------------------
__global__ __launch_bounds__(256) void softmax_kernel(
    const u16* __restrict__ S, u16* __restrict__ P)
{
    const long row = blockIdx.x;
    const int tid = threadIdx.x;

    union { uint4 v; u16 u[8]; } in;
    in.v = ((const uint4*)(S + row * SEQ))[tid];
    float f[8];
#pragma unroll
    for (int j = 0; j < 8; ++j) f[j] = h2f(in.u[j]);

    float m = fmaxf(fmaxf(fmaxf(f[0], f[1]), fmaxf(f[2], f[3])),
                    fmaxf(fmaxf(f[4], f[5]), fmaxf(f[6], f[7])));
#pragma unroll
    for (int off = 32; off; off >>= 1) m = fmaxf(m, __shfl_xor(m, off));

    __shared__ float rm[4], rs[4];
    if ((tid & 63) == 0) rm[tid >> 6] = m;
    __syncthreads();
    m = fmaxf(fmaxf(rm[0], rm[1]), fmaxf(rm[2], rm[3]));

    float e[8], s = 0.0f;
#pragma unroll
    for (int j = 0; j < 8; ++j) { e[j] = expf(f[j] - m); s += e[j]; }
#pragma unroll
    for (int off = 32; off; off >>= 1) s += __shfl_xor(s, off);
    if ((tid & 63) == 0) rs[tid >> 6] = s;
    __syncthreads();
    s = (rs[0] + rs[1]) + (rs[2] + rs[3]);

    const float inv = 1.0f / s;
    union { u16 u[8]; uint4 v; } pk;
#pragma unroll
    for (int j = 0; j < 8; ++j) pk.u[j] = f2h(e[j] * inv);
    *(uint4*)(P + row * SEQ + tid * 8) = pk.v;
}

// ---------------------------------------------------------------------------
// fused residual + layernorm:  h = A + B (B fp16); y = LN(h)*g + be
// ---------------------------------------------------------------------------
template <bool A16, bool OUT16>
__global__ __launch_bounds__(256) void ln_kernel(
    const void* __restrict__ Ain, const u16* __restrict__ Bin,
    const float* __restrict__ g, const float* __restrict__ be,
    void* __restrict__ Out)
{
    const long row = blockIdx.x;
    const int tid = threadIdx.x;

    float a0, a1, a2, a3;
    if constexpr (A16) {
        union { uint2 v; u16 u[4]; } av;
        av.v = ((const uint2*)((const u16*)Ain + row * EMB))[tid];
        a0 = h2f(av.u[0]); a1 = h2f(av.u[1]); a2 = h2f(av.u[2]); a3 = h2f(av.u[3]);
    } else {
        const float4 av = ((const float4*)((const float*)Ain + row * EMB))[tid];
        a0 = av.x; a1 = av.y; a2 = av.z; a3 = av.w;
    }
    union { uint2 v; u16 u[4]; } bv16;
    bv16.v = ((const uint2*)(Bin + row * EMB))[tid];
    const float h0 = a0 + h2f(bv16.u[0]);
    const float h1 = a1 + h2f(bv16.u[1]);
    const float h2 = a2 + h2f(bv16.u[2]);
    const float h3 = a3 + h2f(bv16.u[3]);

    float s = (h0 + h1) + (h2 + h3);
    float q = (h0 * h0 + h1 * h1) + (h2 * h2 + h3 * h3);
#pragma unroll
    for (int off = 32; off; off >>= 1) {
        s += __shfl_xor(s, off);
        q += __shfl_xor(q, off);
    }
    __shared__ float rsm[4], rqm[4];
    if ((tid & 63) == 0) { rsm[tid >> 6] = s; rqm[tid >> 6] = q; }
    __syncthreads();
    s = (rsm[0] + rsm[1]) + (rsm[2] + rsm[3]);
    q = (rqm[0] + rqm[1]) + (rqm[2] + rqm[3]);

    const float mu  = s * (1.0f / EMB);
    const float var = q * (1.0f / EMB) - mu * mu;
    const float rstd = rsqrtf(var + 1e-5f);

    const float4 gv = ((const float4*)g)[tid];
    const float4 bv = ((const float4*)be)[tid];
    const float y0 = (h0 - mu) * rstd * gv.x + bv.x;
    const float y1 = (h1 - mu) * rstd * gv.y + bv.y;
    const float y2 = (h2 - mu) * rstd * gv.z + bv.z;
    const float y3 = (h3 - mu) * rstd * gv.w + bv.w;

    if constexpr (OUT16) {
        union { u16 u[4]; uint2 v; } pk;
        pk.u[0] = f2h(y0); pk.u[1] = f2h(y1);
        pk.u[2] = f2h(y2); pk.u[3] = f2h(y3);
        ((uint2*)((u16*)Out + row * EMB))[tid] = pk.v;
    } else {
        ((float4*)((float*)Out + row * EMB))[tid] = make_float4(y0, y1, y2, y3);
    }
}

// ---------------------------------------------------------------------------
extern "C" void kernel_launch(void* const* d_in, const int* in_sizes, int n_in,
                              void* d_out, int out_size, void* d_ws, size_t ws_size,
                              hipStream_t stream)
{
    const float* src = (const float*)d_in[0];
    const float* Wq  = (const float*)d_in[1];
    const float* bq  = (const float*)d_in[2];
    const float* Wk  = (const float*)d_in[3];
    const float* bk  = (const float*)d_in[4];
    const float* Wv  = (const float*)d_in[5];
    const float* bv  = (const float*)d_in[6];
    const float* Wo  = (const float*)d_in[7];
    const float* bo  = (const float*)d_in[8];
    const float* W1  = (const float*)d_in[9];
    const float* b1  = (const float*)d_in[10];
    const float* W2  = (const float*)d_in[11];
    const float* b2  = (const float*)d_in[12];
    const float* g1  = (const float*)d_in[13];
    const float* be1 = (const float*)d_in[14];
    const float* g2  = (const float*)d_in[15];
    const float* be2 = (const float*)d_in[16];
    float* out = (float*)d_out;

    char* ws = (char*)d_ws;
    const size_t MB = 1ull << 20;
    u16*   WqkT    = (u16*)  (ws + 0 * MB);    // [2048,1024] 4MB
    u16*   WvT     = (u16*)  (ws + 4 * MB);    // [1024,1024] 2MB
    u16*   WoT     = (u16*)  (ws + 6 * MB);    // [1024,1024] 2MB
    u16*   W1T     = (u16*)  (ws + 8 * MB);    // [4096,1024] 8MB
    u16*   W2T     = (u16*)  (ws + 16 * MB);   // [1024,4096] 8MB
    float* bqk     = (float*)(ws + 24 * MB);   // [2048]
    u16*   Xh      = (u16*)  (ws + 25 * MB);   // [8192,1024] 16MB
    u16*   QKh     = (u16*)  (ws + 41 * MB);   // [8192,2048] 32MB
    u16*   Vt      = (u16*)  (ws + 73 * MB);   // [4,1024,2048] 16MB
    u16*   scoresh = (u16*)  (ws + 89 * MB);   // [4,2048,2048] fp16 32MB
    u16*   P       = (u16*)  (ws + 121 * MB);  // [4,2048,2048] fp16 32MB
    u16*   attn    = (u16*)  (ws + 89 * MB);   // 16MB (scoresh dead after softmax)
    u16*   attnp   = (u16*)  (ws + 105 * MB);  // 16MB fp16
    u16*   x       = (u16*)  (ws + 121 * MB);  // 16MB fp16 (P dead after PV)
    u16*   ff1     = (u16*)  (ws + 41 * MB);   // 64MB (QKh/attn dead by FF1)
    u16*   ff2     = (u16*)  (ws + 105 * MB);  // 16MB fp16 (attnp dead after LN1)
    // peak: 153MB

    const int M = BATCH * SEQ;                 // 8192
    const long SS = (long)SEQ * SEQ;           // 4M

    // 1) weights -> fp16 transposed
    tc4<<<dim3(32, 32, 4), 256, 0, stream>>>(Wq, Wk, Wv, Wo, WqkT, WvT, WoT);
    transpose_cast<<<dim3(128, 32, 1), 256, 0, stream>>>(W1, W1T, EMB, FFD);
    transpose_cast<<<dim3(32, 128, 1), 256, 0, stream>>>(W2, W2T, FFD, EMB);
    concat_bias<<<dim3(8), 256, 0, stream>>>(bq, bk, bqk);

    // 2) src -> fp16
    cast_h<<<dim3((M * EMB) / (256 * 8)), 256, 0, stream>>>(src, Xh);

    // 3) QK projection  [8192,2048]
    gemm_8p<u16, false, true><<<dim3(32, 8, 1), 512, 0, stream>>>(
        Xh, WqkT, QKh, bqk, 2048, 1024, 1024, 1024, 2048, 0, 0, 0);

    // 4) Vt = (X Wv + bv)^T directly
    gemm_dp<128, u16, false, 2><<<dim3(8, 8, BATCH), 512, 0, stream>>>(
        WvT, Xh, Vt, bv, SEQ, 1024, 1024, 1024, SEQ,
        0, (long)SEQ * EMB, (long)EMB * SEQ);

    // 5) scores = Q @ K^T per batch (fp16 out)
    gemm_8p<u16, false, false><<<dim3(8, 8, BATCH), 512, 0, stream>>>(
        QKh, QKh + 1024, scoresh, nullptr, SEQ, 1024, 2048, 2048, SEQ,
        (long)SEQ * 2048, (long)SEQ * 2048, SS);

    // 6) softmax -> P fp16
    softmax_kernel<<<dim3(M), 256, 0, stream>>>(scoresh, P);

    // 7) attn = P @ Vt^T per batch
    gemm_dp<128, u16, false, 0><<<dim3(16, 4, BATCH), 512, 0, stream>>>(
        P, Vt, attn, nullptr, EMB, SEQ, SEQ, SEQ, EMB,
        SS, (long)EMB * SEQ, (long)SEQ * EMB);

    // 8) attnp = attn @ Wo^T + bo  (fp16 out)
    gemm_dp<128, u16, false, 1><<<dim3(64, 4, 1), 512, 0, stream>>>(
        attn, WoT, attnp, bo, EMB, EMB, EMB, EMB, EMB, 0, 0, 0);

    // 9) x = LN1(Xh + attnp)
    ln_kernel<true, true><<<dim3(M), 256, 0, stream>>>(
        Xh, attnp, g1, be1, x);

    // 10) ff1 = relu(x @ W1^T + b1)
    gemm_8p<u16, true, true><<<dim3(32, 16, 1), 512, 0, stream>>>(
        x, W1T, ff1, b1, FFD, EMB, EMB, EMB, FFD, 0, 0, 0);

    // 11) ff2 = ff1 @ W2^T + b2  (fp16 out)
    gemm_dp<128, u16, false, 1><<<dim3(64, 4, 1), 512, 0, stream>>>(
        ff1, W2T, ff2, b2, EMB, FFD, FFD, FFD, EMB, 0, 0, 0);

    // 12) out = LN2(x + ff2)  (fp32 out)
    ln_kernel<true, false><<<dim3(M), 256, 0, stream>>>(
        x, ff2, g2, be2, out);
}

// Round 14
// 384.344 us; speedup vs baseline: 1.0051x; 1.0051x over previous
//
#include <hip/hip_runtime.h>
#include <hip/hip_bf16.h>

// ---------------------------------------------------------------------------
// CustomTransformerLayer: QK proj -> scores -> softmax -> PV(fp8) -> Wo -> LN1
//                         -> FF1(relu) -> FF2 -> LN2.
// B=4, S=2048, E=1024, FF=4096.  GEMMs: fp16 MFMA 16x16x32 fp32-acc, except
// PV which runs fp8 e4m3 (P in [0,1], V ~N(0,.64)): same MFMA rate, HALF the
// LDS bytes -> lifts the measured LDS-BW roofline (R13 cycle model).
// ---------------------------------------------------------------------------

using u16 = unsigned short;
using u8  = unsigned char;
typedef __attribute__((ext_vector_type(8))) _Float16 half8;
typedef __attribute__((ext_vector_type(4))) float f32x4;

#define BATCH 4
#define SEQ   2048
#define EMB   1024
#define FFD   4096

#define SWZ(r) ((((r) >> 1) & 3) << 4)

__device__ __forceinline__ u16 f2h(float f) {
    union { _Float16 h; u16 u; } x;
    x.h = (_Float16)f;
    return x.u;
}
__device__ __forceinline__ float h2f(u16 u) {
    union { u16 u; _Float16 h; } x;
    x.u = u;
    return (float)x.h;
}

typedef const __attribute__((address_space(1))) void* gas_ptr;
typedef __attribute__((address_space(3))) void* las_ptr;

__device__ __forceinline__ void load_lds16(const void* g, void* l) {
    __builtin_amdgcn_global_load_lds((gas_ptr)g, (las_ptr)l, 16, 0, 0);
}

// ---------------------------------------------------------------------------
// gemm_8p: 256x256x64 tile, 8 waves (2Mx4N), wave 128x64. [R13 verbatim]
// ---------------------------------------------------------------------------
template <typename OutT, bool RELU, bool BIAS>
__global__ __launch_bounds__(512, 2) void gemm_8p(
    const u16* __restrict__ A, const u16* __restrict__ Bt,
    OutT* __restrict__ C, const float* __restrict__ bias,
    int N, int K, int lda, int ldb, int ldc, long sA, long sB, long sC)
{
    constexpr int BUF = 65536;
    __shared__ __attribute__((aligned(16))) char lds[2 * BUF];

    A  += (long)blockIdx.z * sA;
    Bt += (long)blockIdx.z * sB;
    C  += (long)blockIdx.z * sC;

    const int tid  = threadIdx.x;
    const int lane = tid & 63;
    const int wv   = tid >> 6;
    const int wm   = wv >> 2;
    const int wn   = wv & 3;
    const long row0 = (long)blockIdx.x * 256;
    const long col0 = (long)blockIdx.y * 256;

    long aS[2], bS[2]; int dD[2];
#pragma unroll
    for (int i = 0; i < 2; ++i) {
        const int d16 = i * 512 + tid;
        const int lrow = d16 >> 3;
        const int sl   = d16 & 7;
        const long cswz = (long)((sl ^ (lrow & 7)) << 3);
        aS[i] = (row0 + lrow) * (long)lda + cswz;
        bS[i] = (col0 + lrow) * (long)ldb + cswz;
        dD[i] = d16 * 16;
    }
    const long aHop = 128 * (long)lda;
    const long bHop = 128 * (long)ldb;

    const int klb = (lane >> 4) << 4;
    const int swz = (lane & 7) << 4;
    const int aRB = (wm * 128 + (lane & 15)) * 128 + (klb ^ swz);
    const int bRB = 32768 + (wn * 64 + (lane & 15)) * 128 + (klb ^ swz);

    f32x4 acc[8][4] = {};
    half8 a[8], b[4];
    const int G = K >> 6;

#define SGA(BUFB, H, KT)                                                      \
    { _Pragma("unroll") for (int i_ = 0; i_ < 2; ++i_)                        \
          load_lds16(A + aS[i_] + (H) * aHop + (long)(KT) * 64,               \
                     lds + (BUFB) + (H) * 16384 + dD[i_]); }
#define SGB(BUFB, H, KT)                                                      \
    { _Pragma("unroll") for (int i_ = 0; i_ < 2; ++i_)                        \
          load_lds16(Bt + bS[i_] + (H) * bHop + (long)(KT) * 64,              \
                     lds + (BUFB) + 32768 + (H) * 16384 + dD[i_]); }
#define NOP8 ((void)0)
#define VM8 asm volatile("s_waitcnt vmcnt(8)" ::: "memory")
#define VM6 asm volatile("s_waitcnt vmcnt(6)" ::: "memory")
#define VM2 asm volatile("s_waitcnt vmcnt(2)" ::: "memory")
#define VMZ asm volatile("s_waitcnt vmcnt(0)" ::: "memory")

#define PH8(BUFB, QM, QN, RDA, RDB, STG, VM)                                  \
    {                                                                         \
        if (RDA) {                                                            \
            _Pragma("unroll") for (int m_ = 0; m_ < 4; ++m_)                  \
            _Pragma("unroll") for (int k_ = 0; k_ < 2; ++k_)                  \
                a[m_ * 2 + k_] = *(const half8*)(lds + (BUFB) +               \
                    ((aRB + (QM) * 8192 + m_ * 2048) ^ (k_ << 6)));           \
        }                                                                     \
        if (RDB) {                                                            \
            _Pragma("unroll") for (int n_ = 0; n_ < 2; ++n_)                  \
            _Pragma("unroll") for (int k_ = 0; k_ < 2; ++k_)                  \
                b[n_ * 2 + k_] = *(const half8*)(lds + (BUFB) +               \
                    ((bRB + (QN) * 4096 + n_ * 2048) ^ (k_ << 6)));           \
        }                                                                     \
        STG; VM;                                                              \
        __builtin_amdgcn_s_barrier();                                         \
        __builtin_amdgcn_s_setprio(1);                                        \
        _Pragma("unroll") for (int k_ = 0; k_ < 2; ++k_)                      \
        _Pragma("unroll") for (int m_ = 0; m_ < 4; ++m_)                      \
        _Pragma("unroll") for (int n_ = 0; n_ < 2; ++n_)                      \
            acc[(QM) * 4 + m_][(QN) * 2 + n_] =                               \
                __builtin_amdgcn_mfma_f32_16x16x32_f16(                       \
                    a[m_ * 2 + k_], b[n_ * 2 + k_],                           \
                    acc[(QM) * 4 + m_][(QN) * 2 + n_], 0, 0, 0);              \
        __builtin_amdgcn_s_setprio(0);                                        \
        __builtin_amdgcn_s_barrier();                                         \
    }

    SGA(0, 0, 0); SGB(0, 1, 0); SGB(0, 0, 0); SGA(0, 1, 0);
    SGA(BUF, 0, 1); SGB(BUF, 1, 1);
    VM6;
    __builtin_amdgcn_s_barrier();

    for (int t = 0; t < G - 2; ++t) {
        const int cb = (t & 1) * BUF, ob = cb ^ BUF;
        PH8(cb, 0, 0, 1, 1, SGB(ob, 0, t + 1), NOP8)
        PH8(cb, 0, 1, 0, 1, SGA(ob, 1, t + 1), VM8)
        PH8(cb, 1, 1, 1, 0, SGA(cb, 0, t + 2), NOP8)
        PH8(cb, 1, 0, 0, 1, SGB(cb, 1, t + 2), VM6)
    }
    {
        const int cb = ((G - 2) & 1) * BUF, ob = cb ^ BUF;
        PH8(cb, 0, 0, 1, 1, SGB(ob, 0, G - 1), NOP8)
        PH8(cb, 0, 1, 0, 1, SGA(ob, 1, G - 1), VM8)
        PH8(cb, 1, 1, 1, 0, NOP8, NOP8)
        PH8(cb, 1, 0, 0, 1, NOP8, VM2)
    }
    {
        const int cb = ((G - 1) & 1) * BUF;
        PH8(cb, 0, 0, 1, 1, NOP8, NOP8)
        PH8(cb, 0, 1, 0, 1, NOP8, VMZ)
        PH8(cb, 1, 1, 1, 0, NOP8, NOP8)
        PH8(cb, 1, 0, 0, 1, NOP8, NOP8)
    }
#undef PH8
#undef SGA
#undef SGB
#undef NOP8
#undef VM8
#undef VM6
#undef VM2
#undef VMZ

    long cofs[4]; float bb[4];
#pragma unroll
    for (int n = 0; n < 4; ++n) {
        cofs[n] = col0 + wn * 64 + (n >> 1) * 32 + (n & 1) * 16 + (lane & 15);
        bb[n] = BIAS ? bias[cofs[n]] : 0.0f;
    }
#pragma unroll
    for (int m = 0; m < 8; ++m) {
#pragma unroll
        for (int r = 0; r < 4; ++r) {
            const long row = row0 + wm * 128 + (m >> 2) * 64 + (m & 3) * 16 +
                             ((lane >> 4) << 2) + r;
            OutT* Crow = C + row * (long)ldc;
#pragma unroll
            for (int n = 0; n < 4; ++n) {
                float v = acc[m][n][r] + bb[n];
                if (RELU) v = fmaxf(v, 0.0f);
                if constexpr (sizeof(OutT) == 2)
                    Crow[cofs[n]] = f2h(v);
                else
                    Crow[cofs[n]] = v;
            }
        }
    }
}

// ---------------------------------------------------------------------------
// gemm_dp:  BM x 256 tile, single-phase 32-K slab ring. [R13 structure]
// BMODE: 0 = no bias, 1 = bias[col], 2 = bias[row].  OutT u8 -> fp8 e4m3.
// ---------------------------------------------------------------------------
template <int BM, typename OutT, bool RELU, int BMODE>
__global__ __launch_bounds__(512, 2) void gemm_dp(
    const u16* __restrict__ A, const u16* __restrict__ Bt,
    OutT* __restrict__ C, const float* __restrict__ bias,
    int N, int K, int lda, int ldb, int ldc, long sA, long sB, long sC)
{
    constexpr int MF = BM / 32;
    constexpr int AL = BM / 128;
    constexpr int SLAB_A = BM * 32;
    constexpr int SLAB_B = 256 * 32;

    __shared__ u16 ldsA[4 * SLAB_A];
    __shared__ u16 ldsB[4 * SLAB_B];

    A  += (long)blockIdx.z * sA;
    Bt += (long)blockIdx.z * sB;
    C  += (long)blockIdx.z * sC;

    const int tid  = threadIdx.x;
    const int lane = tid & 63;
    const int wv   = tid >> 6;
    const int wm   = wv >> 2;
    const int wn   = wv & 3;
    const long row0 = (long)blockIdx.x * BM;
    const long col0 = (long)blockIdx.y * 256;

    long aoff[AL]; int adst[AL];
#pragma unroll
    for (int i = 0; i < AL; ++i) {
        const int d16 = i * 512 + tid;
        const int row = d16 >> 2;
        const int colb = ((d16 & 3) << 4) ^ SWZ(row);
        aoff[i] = (row0 + row) * (long)lda + (colb >> 1);
        adst[i] = d16 * 16;
    }
    long boff[2]; int bdst[2];
#pragma unroll
    for (int i = 0; i < 2; ++i) {
        const int d16 = i * 512 + tid;
        const int row = d16 >> 2;
        const int colb = ((d16 & 3) << 4) ^ SWZ(row);
        boff[i] = (col0 + row) * (long)ldb + (colb >> 1);
        bdst[i] = d16 * 16;
    }

    int aro[MF], bro[4];
    const int klane = (lane >> 4) << 4;
#pragma unroll
    for (int m = 0; m < MF; ++m) {
        const int row = wm * (BM / 2) + m * 16 + (lane & 15);
        aro[m] = row * 64 + (klane ^ SWZ(row));
    }
#pragma unroll
    for (int n = 0; n < 4; ++n) {
        const int row = wn * 64 + n * 16 + (lane & 15);
        bro[n] = row * 64 + (klane ^ SWZ(row));
    }

    f32x4 acc[MF][4] = {};
    const int G = K >> 5;

    auto stage = [&](int g) {
        const int slot = g & 3;
        const long k0 = (long)g << 5;
#pragma unroll
        for (int i = 0; i < AL; ++i)
            load_lds16(A + aoff[i] + k0, (char*)ldsA + slot * (SLAB_A * 2) + adst[i]);
#pragma unroll
        for (int i = 0; i < 2; ++i)
            load_lds16(Bt + boff[i] + k0, (char*)ldsB + slot * (SLAB_B * 2) + bdst[i]);
    };

#define VMS asm volatile("s_waitcnt vmcnt(6)" ::: "memory")
#define VMT asm volatile("s_waitcnt vmcnt(3)" ::: "memory")
#define VM0 asm volatile("s_waitcnt vmcnt(0)" ::: "memory")
#define VMNONE ((void)0)

#define GBODY(g, VMASM, DOSTAGE)                                              \
    {                                                                         \
        const int slot_ = (g) & 3;                                            \
        const char* abase_ = (const char*)ldsA + slot_ * (SLAB_A * 2);        \
        const char* bbase_ = (const char*)ldsB + slot_ * (SLAB_B * 2);        \
        half8 a_[MF], b_[4];                                                  \
        _Pragma("unroll") for (int m = 0; m < MF; ++m)                        \
            a_[m] = *(const half8*)(abase_ + aro[m]);                         \
        _Pragma("unroll") for (int n = 0; n < 4; ++n)                         \
            b_[n] = *(const half8*)(bbase_ + bro[n]);                         \
        if (DOSTAGE) stage((g) + 3);                                          \
        VMASM;                                                                \
        __builtin_amdgcn_s_setprio(1);                                        \
        _Pragma("unroll") for (int m = 0; m < MF; ++m)                        \
            _Pragma("unroll") for (int n = 0; n < 4; ++n)                     \
                acc[m][n] = __builtin_amdgcn_mfma_f32_16x16x32_f16(           \
                    a_[m], b_[n], acc[m][n], 0, 0, 0);                        \
        __builtin_amdgcn_s_setprio(0);                                        \
        __builtin_amdgcn_s_barrier();                                         \
    }

    stage(0); stage(1); stage(2);
    VMS;
    __builtin_amdgcn_s_barrier();

    for (int g = 0; g < G - 3; ++g) GBODY(g, VMS, true)
    GBODY(G - 3, VMT, false)
    GBODY(G - 2, VM0, false)
    GBODY(G - 1, VMNONE, false)
#undef GBODY
#undef VMS
#undef VMT
#undef VM0
#undef VMNONE

#pragma unroll
    for (int n = 0; n < 4; ++n) {
        const long col = col0 + wn * 64 + n * 16 + (lane & 15);
        const float bc_ = (BMODE == 1) ? bias[col] : 0.0f;
#pragma unroll
        for (int m = 0; m < MF; ++m) {
            const long row = row0 + wm * (BM / 2) + m * 16 + ((lane >> 4) << 2);
#pragma unroll
            for (int r = 0; r < 4; ++r) {
                float v = acc[m][n][r] + bc_;
                if (BMODE == 2) v += bias[row + r];
                if (RELU) v = fmaxf(v, 0.0f);
                if constexpr (sizeof(OutT) == 1) {
                    const int t = __builtin_amdgcn_cvt_pk_fp8_f32(v, 0.0f, 0, false);
                    C[(row + r) * (long)ldc + col] = (OutT)(t & 0xff);
                } else if constexpr (sizeof(OutT) == 2) {
                    C[(row + r) * (long)ldc + col] = f2h(v);
                } else {
                    C[(row + r) * (long)ldc + col] = v;
                }
            }
        }
    }
}

// ---------------------------------------------------------------------------
// gemm_pv8:  C[M,N](fp16) = A[M,K](fp8) * Bt[N,K](fp8)^T
// 128x256 tile, 8 waves (2Mx4N), wave 64x64.  4-slot ring of 64-fp8 K-slabs
// (A slab 8KB, B slab 16KB; 96KB total).  3 loads/thread/slab -> identical
// 6/3/0 vmcnt counting to gemm_dp.  fp8 frag: 8 fp8/lane via ds b64,
// row=lane&15, k=(lane>>4)*8 (+kk*32), 2-bit chunk swizzle both sides.
// ---------------------------------------------------------------------------
__global__ __launch_bounds__(512, 2) void gemm_pv8(
    const u8* __restrict__ A, const u8* __restrict__ Bt,
    u16* __restrict__ C,
    int N, int K, int lda, int ldb, int ldc, long sA, long sB, long sC)
{
    constexpr int MF = 4;
    constexpr int SLAB_A = 128 * 64;      // bytes
    constexpr int SLAB_B = 256 * 64;      // bytes

    __shared__ __attribute__((aligned(16))) u8 ldsA[4 * SLAB_A];
    __shared__ __attribute__((aligned(16))) u8 ldsB[4 * SLAB_B];

    A  += (long)blockIdx.z * sA;
    Bt += (long)blockIdx.z * sB;
    C  += (long)blockIdx.z * sC;

    const int tid  = threadIdx.x;
    const int lane = tid & 63;
    const int wv   = tid >> 6;
    const int wm   = wv >> 2;
    const int wn   = wv & 3;
    const long row0 = (long)blockIdx.x * 128;
    const long col0 = (long)blockIdx.y * 256;

    // staging: A 512 16B-chunks (1/thread), B 1024 (2/thread); pre-swizzled src
    long aoff; int adst;
    {
        const int d = tid, row = d >> 2, s = d & 3;
        aoff = (row0 + row) * (long)lda + (long)((s ^ (row & 3)) << 4);
        adst = d * 16;
    }
    long boff[2]; int bdst[2];
#pragma unroll
    for (int i = 0; i < 2; ++i) {
        const int d = i * 512 + tid, row = d >> 2, s = d & 3;
        boff[i] = (col0 + row) * (long)ldb + (long)((s ^ (row & 3)) << 4);
        bdst[i] = d * 16;
    }

    // frag read offsets (kk selects via ^ (kk<<5))
    int aro[MF], bro[4];
    const int klg = (lane >> 4) << 3;     // bits 3-4
#pragma unroll
    for (int m = 0; m < MF; ++m) {
        const int row = wm * 64 + m * 16 + (lane & 15);
        aro[m] = row * 64 + (klg ^ ((row & 3) << 4));
    }
#pragma unroll
    for (int n = 0; n < 4; ++n) {
        const int row = wn * 64 + n * 16 + (lane & 15);
        bro[n] = row * 64 + (klg ^ ((row & 3) << 4));
    }

    f32x4 acc[MF][4] = {};
    const int G = K >> 6;                 // 64-fp8 slabs (K=2048 -> 32)

    auto stage = [&](int g) {
        const int slot = g & 3;
        const long k0 = (long)g << 6;
        load_lds16(A + aoff + k0, ldsA + slot * SLAB_A + adst);
#pragma unroll
        for (int i = 0; i < 2; ++i)
            load_lds16(Bt + boff[i] + k0, ldsB + slot * SLAB_B + bdst[i]);
    };

#define VMS asm volatile("s_waitcnt vmcnt(6)" ::: "memory")
#define VMT asm volatile("s_waitcnt vmcnt(3)" ::: "memory")
#define VM0 asm volatile("s_waitcnt vmcnt(0)" ::: "memory")
#define VMNONE ((void)0)

#define GB8(g, VMASM, DOSTAGE)                                                \
    {                                                                         \
        const int slot_ = (g) & 3;                                            \
        const u8* abase_ = ldsA + slot_ * SLAB_A;                             \
        const u8* bbase_ = ldsB + slot_ * SLAB_B;                             \
        long a_[MF][2], b_[4][2];                                             \
        _Pragma("unroll") for (int m = 0; m < MF; ++m)                        \
        _Pragma("unroll") for (int k_ = 0; k_ < 2; ++k_)                      \
            a_[m][k_] = *(const long*)(abase_ + (aro[m] ^ (k_ << 5)));        \
        _Pragma("unroll") for (int n = 0; n < 4; ++n)                         \
        _Pragma("unroll") for (int k_ = 0; k_ < 2; ++k_)                      \
            b_[n][k_] = *(const long*)(bbase_ + (bro[n] ^ (k_ << 5)));        \
        if (DOSTAGE) stage((g) + 3);                                          \
        VMASM;                                                                \
        __builtin_amdgcn_s_setprio(1);                                        \
        _Pragma("unroll") for (int k_ = 0; k_ < 2; ++k_)                      \
        _Pragma("unroll") for (int m = 0; m < MF; ++m)                        \
        _Pragma("unroll") for (int n = 0; n < 4; ++n)                         \
            acc[m][n] = __builtin_amdgcn_mfma_f32_16x16x32_fp8_fp8(           \
                a_[m][k_], b_[n][k_], acc[m][n], 0, 0, 0);                    \
        __builtin_amdgcn_s_setprio(0);                                        \
        __builtin_amdgcn_s_barrier();                                         \
    }

    stage(0); stage(1); stage(2);
    VMS;
    __builtin_amdgcn_s_barrier();

    for (int g = 0; g < G - 3; ++g) GB8(g, VMS, true)
    GB8(G - 3, VMT, false)
    GB8(G - 2, VM0, false)
    GB8(G - 1, VMNONE, false)
#undef GB8
#undef VMS
#undef VMT
#undef VM0
#undef VMNONE

#pragma unroll
    for (int n = 0; n < 4; ++n) {
        const long col = col0 + wn * 64 + n * 16 + (lane & 15);
#pragma unroll
        for (int m = 0; m < MF; ++m) {
            const long row = row0 + wm * 64 + m * 16 + ((lane >> 4) << 2);
#pragma unroll
            for (int r = 0; r < 4; ++r)
                C[(row + r) * (long)ldc + col] = f2h(acc[m][n][r]);
        }
    }
}

// ---------------------------------------------------------------------------
// batched fp32 [1024,1024] -> fp16 transposed:
//   z=0,1 -> WqkT halves; z=2 -> WvT; z=3 -> WoT
// ---------------------------------------------------------------------------
__global__ __launch_bounds__(256) void tc4(
    const float* __restrict__ s0, const float* __restrict__ s1,
    const float* __restrict__ s2, const float* __restrict__ s3,
    u16* __restrict__ dqk, u16* __restrict__ dwv, u16* __restrict__ dwo)
{
    __shared__ float t[32][33];
    const int z = blockIdx.z;
    const float* in = (z == 0) ? s0 : (z == 1) ? s1 : (z == 2) ? s2 : s3;
    u16* out = (z < 2) ? (dqk + (long)z * EMB * EMB) : (z == 2 ? dwv : dwo);
    const int bc = blockIdx.x * 32, br = blockIdx.y * 32;
    const int lx = threadIdx.x & 31, ly = threadIdx.x >> 5;
#pragma unroll
    for (int i = 0; i < 32; i += 8)
        t[ly + i][lx] = in[(long)(br + ly + i) * EMB + bc + lx];
    __syncthreads();
#pragma unroll
    for (int i = 0; i < 32; i += 8)
        out[(long)(bc + ly + i) * EMB + br + lx] = f2h(t[lx][ly + i]);
}

// fp32 [R,C] -> fp16 [C,R] transpose (rect weights)
__global__ __launch_bounds__(256) void transpose_cast(
    const float* __restrict__ in, u16* __restrict__ out, int R, int C)
{
    __shared__ float t[32][33];
    const int bc = blockIdx.x * 32, br = blockIdx.y * 32;
    const int lx = threadIdx.x & 31, ly = threadIdx.x >> 5;
#pragma unroll
    for (int i = 0; i < 32; i += 8)
        t[ly + i][lx] = in[(long)(br + ly + i) * C + bc + lx];
    __syncthreads();
#pragma unroll
    for (int i = 0; i < 32; i += 8)
        out[(long)(bc + ly + i) * R + br + lx] = f2h(t[lx][ly + i]);
}

// fp32 -> fp16 elementwise cast, 8 elems/thread
__global__ __launch_bounds__(256) void cast_h(
    const float* __restrict__ in, u16* __restrict__ out)
{
    const long i = ((long)blockIdx.x * 256 + threadIdx.x) * 8;
    const float4 a = ((const float4*)(in + i))[0];
    const float4 b = ((const float4*)(in + i))[1];
    union { u16 u[8]; uint4 v; } pk;
    pk.u[0] = f2h(a.x); pk.u[1] = f2h(a.y); pk.u[2] = f2h(a.z); pk.u[3] = f2h(a.w);
    pk.u[4] = f2h(b.x); pk.u[5] = f2h(b.y); pk.u[6] = f2h(b.z); pk.u[7] = f2h(b.w);
    *(uint4*)(out + i) = pk.v;
}

// bias concat: [bq|bk] -> 2048 fp32
__global__ __launch_bounds__(256) void concat_bias(
    const float* __restrict__ bq, const float* __restrict__ bk,
    float* __restrict__ o)
{
    const int i = blockIdx.x * 256 + threadIdx.x;
    o[i] = i < 1024 ? bq[i] : bk[i - 1024];
}

// ---------------------------------------------------------------------------
// row softmax: fp16 [rows,2048] -> fp8 e4m3 [rows,2048], one block per row
// ---------------------------------------------------------------------------
__global__ __launch_bounds__(256) void softmax_kernel(
    const u16* __restrict__ S, u8* __restrict__ P)
{
    const long row = blockIdx.x;
    const int tid = threadIdx.x;

    union { uint4 v; u16 u[8]; } in;
    in.v = ((const uint4*)(S + row * SEQ))[tid];
    float f[8];
#pragma unroll
    for (int j = 0; j < 8; ++j) f[j] = h2f(in.u[j]);

    float m = fmaxf(fmaxf(fmaxf(f[0], f[1]), fmaxf(f[2], f[3])),
                    fmaxf(fmaxf(f[4], f[5]), fmaxf(f[6], f[7])));
#pragma unroll
    for (int off = 32; off; off >>= 1) m = fmaxf(m, __shfl_xor(m, off));

    __shared__ float rm[4], rs[4];
    if ((tid & 63) == 0) rm[tid >> 6] = m;
    __syncthreads();
    m = fmaxf(fmaxf(rm[0], rm[1]), fmaxf(rm[2], rm[3]));

    float e[8], s = 0.0f;
#pragma unroll
    for (int j = 0; j < 8; ++j) { e[j] = expf(f[j] - m); s += e[j]; }
#pragma unroll
    for (int off = 32; off; off >>= 1) s += __shfl_xor(s, off);
    if ((tid & 63) == 0) rs[tid >> 6] = s;
    __syncthreads();
    s = (rs[0] + rs[1]) + (rs[2] + rs[3]);

    const float inv = 1.0f / s;
    int lo = 0, hi = 0;
    lo = __builtin_amdgcn_cvt_pk_fp8_f32(e[0] * inv, e[1] * inv, lo, false);
    lo = __builtin_amdgcn_cvt_pk_fp8_f32(e[2] * inv, e[3] * inv, lo, true);
    hi = __builtin_amdgcn_cvt_pk_fp8_f32(e[4] * inv, e[5] * inv, hi, false);
    hi = __builtin_amdgcn_cvt_pk_fp8_f32(e[6] * inv, e[7] * inv, hi, true);
    uint2 pk2; pk2.x = (unsigned)lo; pk2.y = (unsigned)hi;
    *(uint2*)(P + row * SEQ + tid * 8) = pk2;
}

// ---------------------------------------------------------------------------
// fused residual + layernorm:  h = A + B (B fp16); y = LN(h)*g + be
// ---------------------------------------------------------------------------
template <bool A16, bool OUT16>
__global__ __launch_bounds__(256) void ln_kernel(
    const void* __restrict__ Ain, const u16* __restrict__ Bin,
    const float* __restrict__ g, const float* __restrict__ be,
    void* __restrict__ Out)
{
    const long row = blockIdx.x;
    const int tid = threadIdx.x;

    float a0, a1, a2, a3;
    if constexpr (A16) {
        union { uint2 v; u16 u[4]; } av;
        av.v = ((const uint2*)((const u16*)Ain + row * EMB))[tid];
        a0 = h2f(av.u[0]); a1 = h2f(av.u[1]); a2 = h2f(av.u[2]); a3 = h2f(av.u[3]);
    } else {
        const float4 av = ((const float4*)((const float*)Ain + row * EMB))[tid];
        a0 = av.x; a1 = av.y; a2 = av.z; a3 = av.w;
    }
    union { uint2 v; u16 u[4]; } bv16;
    bv16.v = ((const uint2*)(Bin + row * EMB))[tid];
    const float h0 = a0 + h2f(bv16.u[0]);
    const float h1 = a1 + h2f(bv16.u[1]);
    const float h2 = a2 + h2f(bv16.u[2]);
    const float h3 = a3 + h2f(bv16.u[3]);

    float s = (h0 + h1) + (h2 + h3);
    float q = (h0 * h0 + h1 * h1) + (h2 * h2 + h3 * h3);
#pragma unroll
    for (int off = 32; off; off >>= 1) {
        s += __shfl_xor(s, off);
        q += __shfl_xor(q, off);
    }
    __shared__ float rsm[4], rqm[4];
    if ((tid & 63) == 0) { rsm[tid >> 6] = s; rqm[tid >> 6] = q; }
    __syncthreads();
    s = (rsm[0] + rsm[1]) + (rsm[2] + rsm[3]);
    q = (rqm[0] + rqm[1]) + (rqm[2] + rqm[3]);

    const float mu  = s * (1.0f / EMB);
    const float var = q * (1.0f / EMB) - mu * mu;
    const float rstd = rsqrtf(var + 1e-5f);

    const float4 gv = ((const float4*)g)[tid];
    const float4 bv = ((const float4*)be)[tid];
    const float y0 = (h0 - mu) * rstd * gv.x + bv.x;
    const float y1 = (h1 - mu) * rstd * gv.y + bv.y;
    const float y2 = (h2 - mu) * rstd * gv.z + bv.z;
    const float y3 = (h3 - mu) * rstd * gv.w + bv.w;

    if constexpr (OUT16) {
        union { u16 u[4]; uint2 v; } pk;
        pk.u[0] = f2h(y0); pk.u[1] = f2h(y1);
        pk.u[2] = f2h(y2); pk.u[3] = f2h(y3);
        ((uint2*)((u16*)Out + row * EMB))[tid] = pk.v;
    } else {
        ((float4*)((float*)Out + row * EMB))[tid] = make_float4(y0, y1, y2, y3);
    }
}

// ---------------------------------------------------------------------------
extern "C" void kernel_launch(void* const* d_in, const int* in_sizes, int n_in,
                              void* d_out, int out_size, void* d_ws, size_t ws_size,
                              hipStream_t stream)
{
    const float* src = (const float*)d_in[0];
    const float* Wq  = (const float*)d_in[1];
    const float* bq  = (const float*)d_in[2];
    const float* Wk  = (const float*)d_in[3];
    const float* bk  = (const float*)d_in[4];
    const float* Wv  = (const float*)d_in[5];
    const float* bv  = (const float*)d_in[6];
    const float* Wo  = (const float*)d_in[7];
    const float* bo  = (const float*)d_in[8];
    const float* W1  = (const float*)d_in[9];
    const float* b1  = (const float*)d_in[10];
    const float* W2  = (const float*)d_in[11];
    const float* b2  = (const float*)d_in[12];
    const float* g1  = (const float*)d_in[13];
    const float* be1 = (const float*)d_in[14];
    const float* g2  = (const float*)d_in[15];
    const float* be2 = (const float*)d_in[16];
    float* out = (float*)d_out;

    char* ws = (char*)d_ws;
    const size_t MB = 1ull << 20;
    u16*   WqkT    = (u16*)  (ws + 0 * MB);    // [2048,1024] 4MB
    u16*   WvT     = (u16*)  (ws + 4 * MB);    // [1024,1024] 2MB
    u16*   WoT     = (u16*)  (ws + 6 * MB);    // [1024,1024] 2MB
    u16*   W1T     = (u16*)  (ws + 8 * MB);    // [4096,1024] 8MB
    u16*   W2T     = (u16*)  (ws + 16 * MB);   // [1024,4096] 8MB
    float* bqk     = (float*)(ws + 24 * MB);   // [2048]
    u16*   Xh      = (u16*)  (ws + 25 * MB);   // [8192,1024] 16MB
    u16*   QKh     = (u16*)  (ws + 41 * MB);   // [8192,2048] 32MB
    u8*    Vt8     = (u8*)   (ws + 73 * MB);   // [4,1024,2048] fp8 8MB
    u16*   scoresh = (u16*)  (ws + 81 * MB);   // [4,2048,2048] fp16 32MB
    u8*    P8      = (u8*)   (ws + 113 * MB);  // [4,2048,2048] fp8 16MB
    u16*   attn    = (u16*)  (ws + 81 * MB);   // 16MB (scoresh dead after softmax)
    u16*   attnp   = (u16*)  (ws + 97 * MB);   // 16MB fp16
    u16*   x       = (u16*)  (ws + 113 * MB);  // 16MB fp16 (P8 dead after PV)
    u16*   ff1     = (u16*)  (ws + 41 * MB);   // 64MB (QKh/attn/attnp dead by FF1)
    u16*   ff2     = (u16*)  (ws + 129 * MB);  // 16MB fp16
    // peak: 145MB

    const int M = BATCH * SEQ;                 // 8192
    const long SSb = (long)SEQ * SEQ;          // P8 per-batch bytes / scoresh elems

    // 1) weights -> fp16 transposed
    tc4<<<dim3(32, 32, 4), 256, 0, stream>>>(Wq, Wk, Wv, Wo, WqkT, WvT, WoT);
    transpose_cast<<<dim3(128, 32, 1), 256, 0, stream>>>(W1, W1T, EMB, FFD);
    transpose_cast<<<dim3(32, 128, 1), 256, 0, stream>>>(W2, W2T, FFD, EMB);
    concat_bias<<<dim3(8), 256, 0, stream>>>(bq, bk, bqk);

    // 2) src -> fp16
    cast_h<<<dim3((M * EMB) / (256 * 8)), 256, 0, stream>>>(src, Xh);

    // 3) QK projection  [8192,2048]
    gemm_8p<u16, false, true><<<dim3(32, 8, 1), 512, 0, stream>>>(
        Xh, WqkT, QKh, bqk, 2048, 1024, 1024, 1024, 2048, 0, 0, 0);

    // 4) Vt8 = (X Wv + bv)^T directly, fp8 out
    gemm_dp<128, u8, false, 2><<<dim3(8, 8, BATCH), 512, 0, stream>>>(
        WvT, Xh, Vt8, bv, SEQ, 1024, 1024, 1024, SEQ,
        0, (long)SEQ * EMB, (long)EMB * SEQ);

    // 5) scores = Q @ K^T per batch (fp16 out)
    gemm_8p<u16, false, false><<<dim3(8, 8, BATCH), 512, 0, stream>>>(
        QKh, QKh + 1024, scoresh, nullptr, SEQ, 1024, 2048, 2048, SEQ,
        (long)SEQ * 2048, (long)SEQ * 2048, SSb);

    // 6) softmax -> P8 fp8
    softmax_kernel<<<dim3(M), 256, 0, stream>>>(scoresh, P8);

    // 7) attn = P8 @ Vt8^T per batch (fp8 MFMA)
    gemm_pv8<<<dim3(16, 4, BATCH), 512, 0, stream>>>(
        P8, Vt8, attn, EMB, SEQ, SEQ, SEQ, EMB,
        SSb, (long)EMB * SEQ, (long)SEQ * EMB);

    // 8) attnp = attn @ Wo^T + bo  (fp16 out)
    gemm_dp<128, u16, false, 1><<<dim3(64, 4, 1), 512, 0, stream>>>(
        attn, WoT, attnp, bo, EMB, EMB, EMB, EMB, EMB, 0, 0, 0);

    // 9) x = LN1(Xh + attnp)
    ln_kernel<true, true><<<dim3(M), 256, 0, stream>>>(
        Xh, attnp, g1, be1, x);

    // 10) ff1 = relu(x @ W1^T + b1)
    gemm_8p<u16, true, true><<<dim3(32, 16, 1), 512, 0, stream>>>(
        x, W1T, ff1, b1, FFD, EMB, EMB, EMB, FFD, 0, 0, 0);

    // 11) ff2 = ff1 @ W2^T + b2  (fp16 out)
    gemm_dp<128, u16, false, 1><<<dim3(64, 4, 1), 512, 0, stream>>>(
        ff1, W2T, ff2, b2, EMB, FFD, FFD, FFD, EMB, 0, 0, 0);

    // 12) out = LN2(x + ff2)  (fp32 out)
    ln_kernel<true, false><<<dim3(M), 256, 0, stream>>>(
        x, ff2, g2, be2, out);
}